// Round 1
// baseline (628.363 us; speedup 1.0000x reference)
//
#include <hip/hip_runtime.h>
#include <hip/hip_fp16.h>
#include <stdint.h>

typedef _Float16 f16;
typedef _Float16 f16x8 __attribute__((ext_vector_type(8)));
typedef float f32x4 __attribute__((ext_vector_type(4)));

#define NEDGE 1000000
#define BM 128
#define NTHR 512

#define NW1 (128*256)
#define NW2 (256*128)
#define NW3 (64*256)
#define NW4 (5*64)
#define NWTOT (NW1+NW2+NW3+NW4)

// ---------------- weight fp32 -> f16 conversion (into d_ws) ----------------
__global__ __launch_bounds__(512) void wcvt_kernel(
    const float* __restrict__ W1, const float* __restrict__ W2,
    const float* __restrict__ W3, const float* __restrict__ W4,
    f16* __restrict__ dst)
{
    int i = blockIdx.x * 512 + threadIdx.x;
    if (i < NW1)                 dst[i] = (f16)W1[i];
    else if (i < NW1+NW2)        dst[i] = (f16)W2[i-NW1];
    else if (i < NW1+NW2+NW3)    dst[i] = (f16)W3[i-NW1-NW2];
    else if (i < NWTOT)          dst[i] = (f16)W4[i-NW1-NW2-NW3];
}

// swizzled LDS byte address: XOR row-low-bits into the 16B-slot bits (G4 fix
// for stride-512/256/128 bank conflicts). Keeps >=16B alignment classes.
__device__ __forceinline__ uint32_t swz(uint32_t row, uint32_t byteInRow, uint32_t stride) {
    return row * stride + (byteInRow ^ ((row & 7u) << 4));
}

__device__ __forceinline__ f16x8 load_w16(const f16* __restrict__ p) {
    return *(const f16x8*)p;
}
__device__ __forceinline__ f16x8 load_w32(const float* __restrict__ p) {
    float4 a = *(const float4*)p;
    float4 b = *(const float4*)(p + 4);
    f16x8 r;
    r[0]=(f16)a.x; r[1]=(f16)a.y; r[2]=(f16)a.z; r[3]=(f16)a.w;
    r[4]=(f16)b.x; r[5]=(f16)b.y; r[6]=(f16)b.z; r[7]=(f16)b.w;
    return r;
}

// ---------------- fused edge MLP ----------------
// block: 128 edges, 512 threads (8 waves). LDS ping-pong:
//   ldsA: z[128][256] f16 (64KB), later h2[128][256]
//   ldsB: h1[128][128] f16 (32KB), later h3[128][64]
template<bool USE_W16>
__global__ __launch_bounds__(NTHR) void edge_mlp(
    const float* __restrict__ zu, const float* __restrict__ zb,
    const int* __restrict__ eli,
    const float* __restrict__ W1, const float* __restrict__ b1,
    const float* __restrict__ W2, const float* __restrict__ b2,
    const float* __restrict__ W3, const float* __restrict__ b3,
    const float* __restrict__ W4, const float* __restrict__ b4,
    const f16* __restrict__ wsw, float* __restrict__ out)
{
    __shared__ uint4 ldsA4[65536/16];
    __shared__ uint4 ldsB4[32768/16];
    __shared__ int s_row[BM];
    __shared__ int s_col[BM];
    __shared__ int s_flag;

    unsigned char* ldsA = (unsigned char*)ldsA4;
    unsigned char* ldsB = (unsigned char*)ldsB4;

    const int tid  = threadIdx.x;
    const int w    = tid >> 6;
    const int lane = tid & 63;
    const int lr   = lane & 15;   // MFMA row/col index
    const int lq   = lane >> 4;   // MFMA k-group / row-group
    const long long e0 = (long long)blockIdx.x * BM;

    // ---- index dtype sniff (int64 stored little-endian => odd words all 0) ----
    if (tid == 0) s_flag = 1;
    __syncthreads();
    if (tid >= 256) { if (eli[2*(tid-256)+1] != 0) s_flag = 0; }
    __syncthreads();
    const bool idx64 = (s_flag != 0);

    // ---- stage edge indices ----
    if (tid < BM) {
        long long ee = e0 + tid; if (ee >= NEDGE) ee = NEDGE - 1;
        s_row[tid] = idx64 ? eli[2*ee] : eli[ee];
    } else if (tid < 2*BM) {
        int t = tid - BM;
        long long ee = e0 + t; if (ee >= NEDGE) ee = NEDGE - 1;
        s_col[t] = idx64 ? eli[2*((long long)NEDGE + ee)] : eli[(long long)NEDGE + ee];
    }
    __syncthreads();

    // ---- gather: z = concat(z_user[row], z_book[col]) -> f16 swizzled LDS ----
    // each wave handles one edge-row per iteration: lanes 0..31 user half,
    // lanes 32..63 book half; float4 per lane (coalesced 512B+512B).
    #pragma unroll
    for (int i = 0; i < 16; ++i) {
        int row = w + 8*i;
        int col = lane * 4;                      // 0..252 within concat'd 256
        const float* src = (col < 128)
            ? (zu + (size_t)s_row[row]*128 + col)
            : (zb + (size_t)s_col[row]*128 + (col - 128));
        float4 v = *(const float4*)src;
        union { f16 h[4]; uint2 u; } pk;
        pk.h[0]=(f16)v.x; pk.h[1]=(f16)v.y; pk.h[2]=(f16)v.z; pk.h[3]=(f16)v.w;
        *(uint2*)(ldsA + swz((uint32_t)row, (uint32_t)col*2, 512)) = pk.u;
    }
    __syncthreads();

    const int mg = w >> 2;   // 0..1 : row half (64 rows)
    const int ng = w & 3;    // 0..3 : col group

    // ---- layer 1: [128,256] @ W1^T(256->128) + relu -> ldsB h1[128][128] ----
    {
        f32x4 acc[4][2];
        #pragma unroll
        for (int mt = 0; mt < 4; ++mt)
            #pragma unroll
            for (int nt = 0; nt < 2; ++nt) acc[mt][nt] = (f32x4){0.f,0.f,0.f,0.f};
        for (int kk = 0; kk < 8; ++kk) {
            const int kbase = kk*32 + lq*8;
            f16x8 bf[2];
            #pragma unroll
            for (int nt = 0; nt < 2; ++nt) {
                int n = ng*32 + nt*16 + lr;
                bf[nt] = USE_W16 ? load_w16(wsw + n*256 + kbase)
                                 : load_w32(W1 + n*256 + kbase);
            }
            f16x8 af[4];
            #pragma unroll
            for (int mt = 0; mt < 4; ++mt) {
                int row = mg*64 + mt*16 + lr;
                af[mt] = *(const f16x8*)(ldsA + swz((uint32_t)row, (uint32_t)kbase*2, 512));
            }
            #pragma unroll
            for (int mt = 0; mt < 4; ++mt)
                #pragma unroll
                for (int nt = 0; nt < 2; ++nt)
                    acc[mt][nt] = __builtin_amdgcn_mfma_f32_16x16x32_f16(af[mt], bf[nt], acc[mt][nt], 0, 0, 0);
        }
        #pragma unroll
        for (int nt = 0; nt < 2; ++nt) {
            int n = ng*32 + nt*16 + lr;
            float bias = b1[n];
            #pragma unroll
            for (int mt = 0; mt < 4; ++mt)
                #pragma unroll
                for (int j = 0; j < 4; ++j) {
                    float v = fmaxf(acc[mt][nt][j] + bias, 0.f);
                    int row = mg*64 + mt*16 + lq*4 + j;
                    *(f16*)(ldsB + swz((uint32_t)row, (uint32_t)n*2, 256)) = (f16)v;
                }
        }
    }
    __syncthreads();

    // ---- layer 2: h1[128,128] @ W2^T(128->256) + relu -> ldsA h2[128][256] ----
    {
        f32x4 acc[4][4];
        #pragma unroll
        for (int mt = 0; mt < 4; ++mt)
            #pragma unroll
            for (int nt = 0; nt < 4; ++nt) acc[mt][nt] = (f32x4){0.f,0.f,0.f,0.f};
        for (int kk = 0; kk < 4; ++kk) {
            const int kbase = kk*32 + lq*8;
            f16x8 bf[4];
            #pragma unroll
            for (int nt = 0; nt < 4; ++nt) {
                int n = ng*64 + nt*16 + lr;
                bf[nt] = USE_W16 ? load_w16(wsw + NW1 + n*128 + kbase)
                                 : load_w32(W2 + n*128 + kbase);
            }
            f16x8 af[4];
            #pragma unroll
            for (int mt = 0; mt < 4; ++mt) {
                int row = mg*64 + mt*16 + lr;
                af[mt] = *(const f16x8*)(ldsB + swz((uint32_t)row, (uint32_t)kbase*2, 256));
            }
            #pragma unroll
            for (int mt = 0; mt < 4; ++mt)
                #pragma unroll
                for (int nt = 0; nt < 4; ++nt)
                    acc[mt][nt] = __builtin_amdgcn_mfma_f32_16x16x32_f16(af[mt], bf[nt], acc[mt][nt], 0, 0, 0);
        }
        #pragma unroll
        for (int nt = 0; nt < 4; ++nt) {
            int n = ng*64 + nt*16 + lr;
            float bias = b2[n];
            #pragma unroll
            for (int mt = 0; mt < 4; ++mt)
                #pragma unroll
                for (int j = 0; j < 4; ++j) {
                    float v = fmaxf(acc[mt][nt][j] + bias, 0.f);
                    int row = mg*64 + mt*16 + lq*4 + j;
                    *(f16*)(ldsA + swz((uint32_t)row, (uint32_t)n*2, 512)) = (f16)v;
                }
        }
    }
    __syncthreads();

    // ---- layer 3: h2[128,256] @ W3^T(256->64) + relu -> ldsB h3[128][64] ----
    {
        f32x4 acc[4];
        #pragma unroll
        for (int mt = 0; mt < 4; ++mt) acc[mt] = (f32x4){0.f,0.f,0.f,0.f};
        for (int kk = 0; kk < 8; ++kk) {
            const int kbase = kk*32 + lq*8;
            int n = ng*16 + lr;
            f16x8 bf = USE_W16 ? load_w16(wsw + NW1 + NW2 + n*256 + kbase)
                               : load_w32(W3 + n*256 + kbase);
            #pragma unroll
            for (int mt = 0; mt < 4; ++mt) {
                int row = mg*64 + mt*16 + lr;
                f16x8 af = *(const f16x8*)(ldsA + swz((uint32_t)row, (uint32_t)kbase*2, 512));
                acc[mt] = __builtin_amdgcn_mfma_f32_16x16x32_f16(af, bf, acc[mt], 0, 0, 0);
            }
        }
        {
            int n = ng*16 + lr;
            float bias = b3[n];
            #pragma unroll
            for (int mt = 0; mt < 4; ++mt)
                #pragma unroll
                for (int j = 0; j < 4; ++j) {
                    float v = fmaxf(acc[mt][j] + bias, 0.f);
                    int row = mg*64 + mt*16 + lq*4 + j;
                    *(f16*)(ldsB + swz((uint32_t)row, (uint32_t)n*2, 128)) = (f16)v;
                }
        }
    }
    __syncthreads();

    // ---- layer 4: h3[128,64] @ W4^T(64->5) + b4 -> staged f32 out ----
    {
        f32x4 acc = (f32x4){0.f,0.f,0.f,0.f};
        #pragma unroll
        for (int kk = 0; kk < 2; ++kk) {
            const int kbase = kk*32 + lq*8;
            int row = w*16 + lr;
            f16x8 af = *(const f16x8*)(ldsB + swz((uint32_t)row, (uint32_t)kbase*2, 128));
            f16x8 bf;
            if (lr < 5) {
                bf = USE_W16 ? load_w16(wsw + NW1 + NW2 + NW3 + lr*64 + kbase)
                             : load_w32(W4 + lr*64 + kbase);
            } else {
                #pragma unroll
                for (int jj = 0; jj < 8; ++jj) bf[jj] = (f16)0;
            }
            acc = __builtin_amdgcn_mfma_f32_16x16x32_f16(af, bf, acc, 0, 0, 0);
        }
        float* ldsOut = (float*)ldsA;  // ldsA free after layer-3 reads
        if (lr < 5) {
            float bias = b4[lr];
            #pragma unroll
            for (int j = 0; j < 4; ++j) {
                int row = w*16 + lq*4 + j;
                ldsOut[row*5 + lr] = acc[j] + bias;
            }
        }
    }
    __syncthreads();

    // ---- coalesced store ----
    {
        long long rem = (long long)NEDGE - e0;
        int ev = rem < BM ? (int)rem : BM;
        const float* ldsOut = (const float*)ldsA;
        for (int t = tid; t < ev*5; t += NTHR) out[e0*5 + t] = ldsOut[t];
    }
}

extern "C" void kernel_launch(void* const* d_in, const int* in_sizes, int n_in,
                              void* d_out, int out_size, void* d_ws, size_t ws_size,
                              hipStream_t stream) {
    const float* zu  = (const float*)d_in[0];
    const float* zb  = (const float*)d_in[1];
    const int*   eli = (const int*)d_in[2];
    const float* W1  = (const float*)d_in[3];
    const float* b1  = (const float*)d_in[4];
    const float* W2  = (const float*)d_in[5];
    const float* b2  = (const float*)d_in[6];
    const float* W3  = (const float*)d_in[7];
    const float* b3  = (const float*)d_in[8];
    const float* W4  = (const float*)d_in[9];
    const float* b4  = (const float*)d_in[10];
    float* out = (float*)d_out;

    const int grid = (NEDGE + BM - 1) / BM;  // 7813
    const bool w16 = (ws_size >= (size_t)NWTOT * sizeof(f16));

    if (w16) {
        wcvt_kernel<<<(NWTOT + 511)/512, 512, 0, stream>>>(W1, W2, W3, W4, (f16*)d_ws);
        edge_mlp<true><<<grid, NTHR, 0, stream>>>(zu, zb, eli, W1, b1, W2, b2, W3, b3, W4, b4,
                                                  (const f16*)d_ws, out);
    } else {
        edge_mlp<false><<<grid, NTHR, 0, stream>>>(zu, zb, eli, W1, b1, W2, b2, W3, b3, W4, b4,
                                                   (const f16*)nullptr, out);
    }
}

// Round 2
// 600.730 us; speedup vs baseline: 1.0460x; 1.0460x over previous
//
#include <hip/hip_runtime.h>
#include <hip/hip_fp16.h>
#include <stdint.h>

typedef _Float16 f16;
typedef _Float16 f16x8 __attribute__((ext_vector_type(8)));
typedef float f32x4 __attribute__((ext_vector_type(4)));

#define NEDGE 1000000
#define BM 96            // 96 edges/block -> 73KB LDS -> 2 blocks/CU (was 128 -> 99.8KB -> 1 block/CU)
#define NTHR 512

#define NW1 (128*256)
#define NW2 (256*128)
#define NW3 (64*256)
#define NW4 (5*64)
#define NWTOT (NW1+NW2+NW3+NW4)

// ---------------- weight fp32 -> f16 conversion (into d_ws) ----------------
__global__ __launch_bounds__(512) void wcvt_kernel(
    const float* __restrict__ W1, const float* __restrict__ W2,
    const float* __restrict__ W3, const float* __restrict__ W4,
    f16* __restrict__ dst)
{
    int i = blockIdx.x * 512 + threadIdx.x;
    if (i < NW1)                 dst[i] = (f16)W1[i];
    else if (i < NW1+NW2)        dst[i] = (f16)W2[i-NW1];
    else if (i < NW1+NW2+NW3)    dst[i] = (f16)W3[i-NW1-NW2];
    else if (i < NWTOT)          dst[i] = (f16)W4[i-NW1-NW2-NW3];
}

// swizzled LDS byte address: XOR row-low-bits into the 16B-slot bits (G4 fix
// for stride-512/256/128 bank conflicts). Keeps >=16B alignment classes.
__device__ __forceinline__ uint32_t swz(uint32_t row, uint32_t byteInRow, uint32_t stride) {
    return row * stride + (byteInRow ^ ((row & 7u) << 4));
}

__device__ __forceinline__ f16x8 load_w16(const f16* __restrict__ p) {
    return *(const f16x8*)p;
}
__device__ __forceinline__ f16x8 load_w32(const float* __restrict__ p) {
    float4 a = *(const float4*)p;
    float4 b = *(const float4*)(p + 4);
    f16x8 r;
    r[0]=(f16)a.x; r[1]=(f16)a.y; r[2]=(f16)a.z; r[3]=(f16)a.w;
    r[4]=(f16)b.x; r[5]=(f16)b.y; r[6]=(f16)b.z; r[7]=(f16)b.w;
    return r;
}

// ---------------- fused edge MLP ----------------
// block: 96 edges, 512 threads (8 waves). LDS ping-pong:
//   ldsA: z[96][256] f16 (48KB), later h2[96][256], later f32 out staging
//   ldsB: h1[96][128] f16 (24KB), later h3[96][64]
// Wave tiling: mg = w>>2 picks 48-row half (3 m-tiles of 16), ng = w&3 picks
// column group. bf reuse stays 3-4 MFMA per weight fragment load.
template<bool USE_W16>
__global__ __launch_bounds__(NTHR, 4) void edge_mlp(
    const float* __restrict__ zu, const float* __restrict__ zb,
    const int* __restrict__ eli,
    const float* __restrict__ W1, const float* __restrict__ b1,
    const float* __restrict__ W2, const float* __restrict__ b2,
    const float* __restrict__ W3, const float* __restrict__ b3,
    const float* __restrict__ W4, const float* __restrict__ b4,
    const f16* __restrict__ wsw, float* __restrict__ out)
{
    __shared__ uint4 ldsA4[49152/16];
    __shared__ uint4 ldsB4[24576/16];
    __shared__ int s_row[BM];
    __shared__ int s_col[BM];
    __shared__ int s_flag;

    unsigned char* ldsA = (unsigned char*)ldsA4;
    unsigned char* ldsB = (unsigned char*)ldsB4;

    const int tid  = threadIdx.x;
    const int w    = tid >> 6;
    const int lane = tid & 63;
    const int lr   = lane & 15;   // MFMA row/col index
    const int lq   = lane >> 4;   // MFMA k-group / row-group
    const long long e0 = (long long)blockIdx.x * BM;

    // ---- index dtype sniff (int64 stored little-endian => odd words all 0) ----
    if (tid == 0) s_flag = 1;
    __syncthreads();
    if (tid >= 256) { if (eli[2*(tid-256)+1] != 0) s_flag = 0; }
    __syncthreads();
    const bool idx64 = (s_flag != 0);

    // ---- stage edge indices ----
    if (tid < BM) {
        long long ee = e0 + tid; if (ee >= NEDGE) ee = NEDGE - 1;
        s_row[tid] = idx64 ? eli[2*ee] : eli[ee];
    } else if (tid < 2*BM) {
        int t = tid - BM;
        long long ee = e0 + t; if (ee >= NEDGE) ee = NEDGE - 1;
        s_col[t] = idx64 ? eli[2*((long long)NEDGE + ee)] : eli[(long long)NEDGE + ee];
    }
    __syncthreads();

    // ---- gather: z = concat(z_user[row], z_book[col]) -> f16 swizzled LDS ----
    // each wave handles one edge-row per iteration: lanes 0..31 user half,
    // lanes 32..63 book half; float4 per lane (coalesced 512B+512B).
    #pragma unroll
    for (int i = 0; i < BM/8; ++i) {
        int row = w + 8*i;
        int col = lane * 4;                      // 0..252 within concat'd 256
        const float* src = (col < 128)
            ? (zu + (size_t)s_row[row]*128 + col)
            : (zb + (size_t)s_col[row]*128 + (col - 128));
        float4 v = *(const float4*)src;
        union { f16 h[4]; uint2 u; } pk;
        pk.h[0]=(f16)v.x; pk.h[1]=(f16)v.y; pk.h[2]=(f16)v.z; pk.h[3]=(f16)v.w;
        *(uint2*)(ldsA + swz((uint32_t)row, (uint32_t)col*2, 512)) = pk.u;
    }
    __syncthreads();

    const int mg = w >> 2;   // 0..1 : row half (48 rows = 3 m-tiles)
    const int ng = w & 3;    // 0..3 : col group

    // ---- layer 1: [96,256] @ W1^T(256->128) + relu -> ldsB h1[96][128] ----
    {
        f32x4 acc[3][2];
        #pragma unroll
        for (int mt = 0; mt < 3; ++mt)
            #pragma unroll
            for (int nt = 0; nt < 2; ++nt) acc[mt][nt] = (f32x4){0.f,0.f,0.f,0.f};
        for (int kk = 0; kk < 8; ++kk) {
            const int kbase = kk*32 + lq*8;
            f16x8 bf[2];
            #pragma unroll
            for (int nt = 0; nt < 2; ++nt) {
                int n = ng*32 + nt*16 + lr;
                bf[nt] = USE_W16 ? load_w16(wsw + n*256 + kbase)
                                 : load_w32(W1 + n*256 + kbase);
            }
            f16x8 af[3];
            #pragma unroll
            for (int mt = 0; mt < 3; ++mt) {
                int row = mg*48 + mt*16 + lr;
                af[mt] = *(const f16x8*)(ldsA + swz((uint32_t)row, (uint32_t)kbase*2, 512));
            }
            #pragma unroll
            for (int mt = 0; mt < 3; ++mt)
                #pragma unroll
                for (int nt = 0; nt < 2; ++nt)
                    acc[mt][nt] = __builtin_amdgcn_mfma_f32_16x16x32_f16(af[mt], bf[nt], acc[mt][nt], 0, 0, 0);
        }
        #pragma unroll
        for (int nt = 0; nt < 2; ++nt) {
            int n = ng*32 + nt*16 + lr;
            float bias = b1[n];
            #pragma unroll
            for (int mt = 0; mt < 3; ++mt)
                #pragma unroll
                for (int j = 0; j < 4; ++j) {
                    float v = fmaxf(acc[mt][nt][j] + bias, 0.f);
                    int row = mg*48 + mt*16 + lq*4 + j;
                    *(f16*)(ldsB + swz((uint32_t)row, (uint32_t)n*2, 256)) = (f16)v;
                }
        }
    }
    __syncthreads();

    // ---- layer 2: h1[96,128] @ W2^T(128->256) + relu -> ldsA h2[96][256] ----
    {
        f32x4 acc[3][4];
        #pragma unroll
        for (int mt = 0; mt < 3; ++mt)
            #pragma unroll
            for (int nt = 0; nt < 4; ++nt) acc[mt][nt] = (f32x4){0.f,0.f,0.f,0.f};
        for (int kk = 0; kk < 4; ++kk) {
            const int kbase = kk*32 + lq*8;
            f16x8 bf[4];
            #pragma unroll
            for (int nt = 0; nt < 4; ++nt) {
                int n = ng*64 + nt*16 + lr;
                bf[nt] = USE_W16 ? load_w16(wsw + NW1 + n*128 + kbase)
                                 : load_w32(W2 + n*128 + kbase);
            }
            f16x8 af[3];
            #pragma unroll
            for (int mt = 0; mt < 3; ++mt) {
                int row = mg*48 + mt*16 + lr;
                af[mt] = *(const f16x8*)(ldsB + swz((uint32_t)row, (uint32_t)kbase*2, 256));
            }
            #pragma unroll
            for (int mt = 0; mt < 3; ++mt)
                #pragma unroll
                for (int nt = 0; nt < 4; ++nt)
                    acc[mt][nt] = __builtin_amdgcn_mfma_f32_16x16x32_f16(af[mt], bf[nt], acc[mt][nt], 0, 0, 0);
        }
        #pragma unroll
        for (int nt = 0; nt < 4; ++nt) {
            int n = ng*64 + nt*16 + lr;
            float bias = b2[n];
            #pragma unroll
            for (int mt = 0; mt < 3; ++mt)
                #pragma unroll
                for (int j = 0; j < 4; ++j) {
                    float v = fmaxf(acc[mt][nt][j] + bias, 0.f);
                    int row = mg*48 + mt*16 + lq*4 + j;
                    *(f16*)(ldsA + swz((uint32_t)row, (uint32_t)n*2, 512)) = (f16)v;
                }
        }
    }
    __syncthreads();

    // ---- layer 3: h2[96,256] @ W3^T(256->64) + relu -> ldsB h3[96][64] ----
    {
        f32x4 acc[3];
        #pragma unroll
        for (int mt = 0; mt < 3; ++mt) acc[mt] = (f32x4){0.f,0.f,0.f,0.f};
        for (int kk = 0; kk < 8; ++kk) {
            const int kbase = kk*32 + lq*8;
            int n = ng*16 + lr;
            f16x8 bf = USE_W16 ? load_w16(wsw + NW1 + NW2 + n*256 + kbase)
                               : load_w32(W3 + n*256 + kbase);
            #pragma unroll
            for (int mt = 0; mt < 3; ++mt) {
                int row = mg*48 + mt*16 + lr;
                f16x8 af = *(const f16x8*)(ldsA + swz((uint32_t)row, (uint32_t)kbase*2, 512));
                acc[mt] = __builtin_amdgcn_mfma_f32_16x16x32_f16(af, bf, acc[mt], 0, 0, 0);
            }
        }
        {
            int n = ng*16 + lr;
            float bias = b3[n];
            #pragma unroll
            for (int mt = 0; mt < 3; ++mt)
                #pragma unroll
                for (int j = 0; j < 4; ++j) {
                    float v = fmaxf(acc[mt][j] + bias, 0.f);
                    int row = mg*48 + mt*16 + lq*4 + j;
                    *(f16*)(ldsB + swz((uint32_t)row, (uint32_t)n*2, 128)) = (f16)v;
                }
        }
    }
    __syncthreads();

    // ---- layer 4: h3[96,64] @ W4^T(64->5) + b4 -> staged f32 out ----
    // 6 m-tiles of 16 rows; waves 0..5 take one each, waves 6..7 idle.
    {
        float* ldsOut = (float*)ldsA;  // ldsA free after layer-3 reads
        if (w < 6) {
            f32x4 acc = (f32x4){0.f,0.f,0.f,0.f};
            #pragma unroll
            for (int kk = 0; kk < 2; ++kk) {
                const int kbase = kk*32 + lq*8;
                int row = w*16 + lr;
                f16x8 af = *(const f16x8*)(ldsB + swz((uint32_t)row, (uint32_t)kbase*2, 128));
                f16x8 bf;
                if (lr < 5) {
                    bf = USE_W16 ? load_w16(wsw + NW1 + NW2 + NW3 + lr*64 + kbase)
                                 : load_w32(W4 + lr*64 + kbase);
                } else {
                    #pragma unroll
                    for (int jj = 0; jj < 8; ++jj) bf[jj] = (f16)0;
                }
                acc = __builtin_amdgcn_mfma_f32_16x16x32_f16(af, bf, acc, 0, 0, 0);
            }
            if (lr < 5) {
                float bias = b4[lr];
                #pragma unroll
                for (int j = 0; j < 4; ++j) {
                    int row = w*16 + lq*4 + j;
                    ldsOut[row*5 + lr] = acc[j] + bias;
                }
            }
        }
    }
    __syncthreads();

    // ---- coalesced store ----
    {
        long long rem = (long long)NEDGE - e0;
        int ev = rem < BM ? (int)rem : BM;
        const float* ldsOut = (const float*)ldsA;
        for (int t = tid; t < ev*5; t += NTHR) out[e0*5 + t] = ldsOut[t];
    }
}

extern "C" void kernel_launch(void* const* d_in, const int* in_sizes, int n_in,
                              void* d_out, int out_size, void* d_ws, size_t ws_size,
                              hipStream_t stream) {
    const float* zu  = (const float*)d_in[0];
    const float* zb  = (const float*)d_in[1];
    const int*   eli = (const int*)d_in[2];
    const float* W1  = (const float*)d_in[3];
    const float* b1  = (const float*)d_in[4];
    const float* W2  = (const float*)d_in[5];
    const float* b2  = (const float*)d_in[6];
    const float* W3  = (const float*)d_in[7];
    const float* b3  = (const float*)d_in[8];
    const float* W4  = (const float*)d_in[9];
    const float* b4  = (const float*)d_in[10];
    float* out = (float*)d_out;

    const int grid = (NEDGE + BM - 1) / BM;  // 10417
    const bool w16 = (ws_size >= (size_t)NWTOT * sizeof(f16));

    if (w16) {
        wcvt_kernel<<<(NWTOT + 511)/512, 512, 0, stream>>>(W1, W2, W3, W4, (f16*)d_ws);
        edge_mlp<true><<<grid, NTHR, 0, stream>>>(zu, zb, eli, W1, b1, W2, b2, W3, b3, W4, b4,
                                                  (const f16*)d_ws, out);
    } else {
        edge_mlp<false><<<grid, NTHR, 0, stream>>>(zu, zb, eli, W1, b1, W2, b2, W3, b3, W4, b4,
                                                   (const f16*)nullptr, out);
    }
}